// Round 8
// baseline (320.516 us; speedup 1.0000x reference)
//
#include <hip/hip_runtime.h>

#define NN 50000
#define NE 400000
#define NPB 16                       // src nodes per fused block (16 | 256 alloc chunk)
#define NSB (NN / NPB)               // 3125 fused blocks
#define YSTRIDE 276                  // 272 + pad
#define ALLOC_BLKS ((NN + 255) / 256)  // 196 per side

// ws layout (4B units):
//   msg1     float [16*NE]
//   msg2     float [16*NE]
//   h1       float [16*NN]
//   dstdeg   int   [NN]      (memset zeroes dstdeg, srcdeg, gcur)
//   srcdeg   int   [NN]
//   gcur     int   [2]
//   base_dst int   [NN]
//   cur_dst  int   [NN]
//   nb_src   int   [NN]
//   cur_src  int   [NN]
//   ordsrc   int2  [NE]   {eid | (local_node<<19), dst slot}

__global__ __launch_bounds__(256) void hist_kernel(
    const int* __restrict__ eidx, int* __restrict__ dstdeg,
    int* __restrict__ srcdeg)
{
    int e = blockIdx.x * 256 + threadIdx.x;
    if (e < NE) {
        atomicAdd(&srcdeg[eidx[e]], 1);
        atomicAdd(&dstdeg[eidx[NE + e]], 1);
    }
}

__device__ __forceinline__ int block_excl_scan_256(int v, int tid)
{
    __shared__ int wsum[4];
    int lane = tid & 63, w = tid >> 6;
    int incl = v;
#pragma unroll
    for (int d = 1; d < 64; d <<= 1) {
        int t = __shfl_up(incl, d, 64);
        if (lane >= d) incl += t;
    }
    if (lane == 63) wsum[w] = incl;
    __syncthreads();
    if (tid == 0) {
        int s = 0;
#pragma unroll
        for (int k = 0; k < 4; ++k) { int t = wsum[k]; wsum[k] = s; s += t; }
    }
    __syncthreads();
    return incl - v + wsum[w];
}

// Contiguous (globally unordered) range alloc: 256-node chunks, 1 atomic each.
// Blocks [0,ALLOC_BLKS): dst nodes; [ALLOC_BLKS, 2*ALLOC_BLKS): src nodes.
// Within a chunk nodes are ordered, and 16 | 256, so each fused block's 16
// src nodes occupy one contiguous slot range.
__global__ __launch_bounds__(256) void alloc_kernel(
    const int* __restrict__ dstdeg, const int* __restrict__ srcdeg,
    int* __restrict__ gcur,
    int* __restrict__ base_dst, int* __restrict__ cur_dst,
    int* __restrict__ nb_src, int* __restrict__ cur_src)
{
    __shared__ int base_s;
    int tid = threadIdx.x;
    bool isdst = blockIdx.x < ALLOC_BLKS;
    int i = (isdst ? blockIdx.x : blockIdx.x - ALLOC_BLKS) * 256 + tid;
    int v = (i < NN) ? (isdst ? dstdeg[i] : srcdeg[i]) : 0;
    int excl = block_excl_scan_256(v, tid);
    if (tid == 255) base_s = atomicAdd(isdst ? &gcur[0] : &gcur[1], excl + v);
    __syncthreads();
    int base = base_s + excl;
    if (i < NN) {
        if (isdst) { base_dst[i] = base; cur_dst[i] = base; }
        else       { nb_src[i] = base;  cur_src[i] = base; }
    }
}

__global__ __launch_bounds__(256) void fill_kernel(
    const int* __restrict__ eidx, int* __restrict__ cur_dst,
    int* __restrict__ cur_src, int2* __restrict__ ordsrc)
{
    int e = blockIdx.x * 256 + threadIdx.x;
    if (e < NE) {
        int s = eidx[e], d = eidx[NE + e];
        int ps = atomicAdd(&cur_src[s], 1);
        int pd = atomicAdd(&cur_dst[d], 1);
        ordsrc[ps] = make_int2(e | ((s & 15) << 19), pd);
    }
}

// ---------------------------------------------------------------------------
// Fused edge machinery. Block = 16 src nodes; LDS 18.7 KB -> 8 blocks/CU.
// ---------------------------------------------------------------------------
struct FusedSmem {
    float xl[NPB * 16];
    float Yl[NPB * YSTRIDE];
};

__device__ __forceinline__ void fused_core(
    FusedSmem& sm, int tid, int j0, int j1,
    const float* __restrict__ ea,
    const int2* __restrict__ ordsrc,
    const float* __restrict__ w1, const float* __restrict__ b1,
    const float* __restrict__ w2, const float* __restrict__ b2,
    float* __restrict__ msg_out)
{
    int o = tid & 15;

    // phase 1a: thread (k,o) holds its 16 w2 weights, loops 16 nodes
    {
        int k = tid >> 4;
        float w[16];
#pragma unroll
        for (int i = 0; i < 16; ++i) w[i] = w2[k * 256 + i * 16 + o];
#pragma unroll 4
        for (int node = 0; node < NPB; ++node) {
            const float4* xr = (const float4*)&sm.xl[node * 16];
            float4 x0 = xr[0], x1 = xr[1], x2 = xr[2], x3 = xr[3];
            float acc = x0.x * w[0] + x0.y * w[1] + x0.z * w[2] + x0.w * w[3]
                      + x1.x * w[4] + x1.y * w[5] + x1.z * w[6] + x1.w * w[7]
                      + x2.x * w[8] + x2.y * w[9] + x2.z * w[10] + x2.w * w[11]
                      + x3.x * w[12] + x3.y * w[13] + x3.z * w[14] + x3.w * w[15];
            sm.Yl[node * YSTRIDE + k * 16 + o] = acc;
        }
    }
    // phase 1b: Y0 (=b2) slice; thread (node,o)
    {
        int node = tid >> 4;
        float w[16];
#pragma unroll
        for (int i = 0; i < 16; ++i) w[i] = b2[i * 16 + o];
        const float4* xr = (const float4*)&sm.xl[node * 16];
        float4 x0 = xr[0], x1 = xr[1], x2 = xr[2], x3 = xr[3];
        float acc = x0.x * w[0] + x0.y * w[1] + x0.z * w[2] + x0.w * w[3]
                  + x1.x * w[4] + x1.y * w[5] + x1.z * w[6] + x1.w * w[7]
                  + x2.x * w[8] + x2.y * w[9] + x2.z * w[10] + x2.w * w[11]
                  + x3.x * w[12] + x3.y * w[13] + x3.z * w[14] + x3.w * w[15];
        sm.Yl[node * YSTRIDE + 256 + o] = acc;
    }
    __syncthreads();

    // phase 2: one thread per src slot
    for (int j = j0 + tid; j < j1; j += 256) {
        int2 od = ordsrc[j];
        int e = od.x & 0x7FFFF;
        int node = od.x >> 19;
        int pd = od.y;

        const float4* av = (const float4*)(ea + (size_t)e * 8);
        float4 a0 = av[0], a1 = av[1];
        float a[8] = {a0.x, a0.y, a0.z, a0.w, a1.x, a1.y, a1.z, a1.w};

        float hid[16];
#pragma unroll
        for (int jj = 0; jj < 16; ++jj) hid[jj] = b1[jj];
#pragma unroll
        for (int c = 0; c < 8; ++c)
#pragma unroll
            for (int jj = 0; jj < 16; ++jj) hid[jj] += a[c] * w1[c * 16 + jj];
#pragma unroll
        for (int jj = 0; jj < 16; ++jj) hid[jj] = fmaxf(hid[jj], 0.0f);

        const float4* Yr = (const float4*)&sm.Yl[node * YSTRIDE];
        float4 m0 = Yr[64], m1 = Yr[65], m2 = Yr[66], m3 = Yr[67];
#pragma unroll
        for (int k = 0; k < 16; ++k) {
            float hk = hid[k];
            float4 y0 = Yr[k * 4 + 0], y1 = Yr[k * 4 + 1];
            float4 y2 = Yr[k * 4 + 2], y3 = Yr[k * 4 + 3];
            m0.x = fmaf(hk, y0.x, m0.x); m0.y = fmaf(hk, y0.y, m0.y);
            m0.z = fmaf(hk, y0.z, m0.z); m0.w = fmaf(hk, y0.w, m0.w);
            m1.x = fmaf(hk, y1.x, m1.x); m1.y = fmaf(hk, y1.y, m1.y);
            m1.z = fmaf(hk, y1.z, m1.z); m1.w = fmaf(hk, y1.w, m1.w);
            m2.x = fmaf(hk, y2.x, m2.x); m2.y = fmaf(hk, y2.y, m2.y);
            m2.z = fmaf(hk, y2.z, m2.z); m2.w = fmaf(hk, y2.w, m2.w);
            m3.x = fmaf(hk, y3.x, m3.x); m3.y = fmaf(hk, y3.y, m3.y);
            m3.z = fmaf(hk, y3.z, m3.z); m3.w = fmaf(hk, y3.w, m3.w);
        }
        float4* mp = (float4*)(msg_out + (size_t)pd * 16);
        mp[0] = m0; mp[1] = m1; mp[2] = m2; mp[3] = m3;
    }
}

__global__ __launch_bounds__(256, 8) void edge_fused1(
    const float* __restrict__ xin, const float* __restrict__ ea,
    const int2* __restrict__ ordsrc,
    const int* __restrict__ nb_src, const int* __restrict__ srcdeg,
    const float* __restrict__ w1, const float* __restrict__ b1,
    const float* __restrict__ w2, const float* __restrict__ b2,
    float* __restrict__ msg)
{
    __shared__ FusedSmem sm;
    int tid = threadIdx.x;
    int n0 = blockIdx.x * NPB;

    sm.xl[tid] = xin[(size_t)n0 * 16 + tid];
    int j0 = nb_src[n0];
    int j1 = nb_src[n0 + NPB - 1] + srcdeg[n0 + NPB - 1];
    __syncthreads();

    fused_core(sm, tid, j0, j1, ea, ordsrc, w1, b1, w2, b2, msg);
}

// Layer 2 with fused h1 computation: prologue builds h1 rows for this block's
// 16 nodes (gather-mean msg1 + x@root1 + bias1, relu) into sm.xl and h1g.
__global__ __launch_bounds__(256, 8) void edge_fused2(
    const float* __restrict__ xin, const float* __restrict__ msg1,
    const int* __restrict__ base_dst, const int* __restrict__ dstdeg,
    const float* __restrict__ root1, const float* __restrict__ bias1,
    float* __restrict__ h1g,
    const float* __restrict__ ea,
    const int2* __restrict__ ordsrc,
    const int* __restrict__ nb_src, const int* __restrict__ srcdeg,
    const float* __restrict__ w1, const float* __restrict__ b1,
    const float* __restrict__ w2, const float* __restrict__ b2,
    float* __restrict__ msg2)
{
    __shared__ FusedSmem sm;
    int tid = threadIdx.x;
    int n0 = blockIdx.x * NPB;
    int node = tid >> 4, o = tid & 15;
    int gn = n0 + node;

    // h1 prologue: (node,o) covers all 16x16 entries
    {
        int jd0 = base_dst[gn], deg = dstdeg[gn], jd1 = jd0 + deg;
        float s0 = 0.0f, s1 = 0.0f;
        int j = jd0;
        for (; j + 1 < jd1; j += 2) {
            s0 += msg1[(size_t)j * 16 + o];
            s1 += msg1[(size_t)(j + 1) * 16 + o];
        }
        if (j < jd1) s0 += msg1[(size_t)j * 16 + o];
        float inv = 1.0f / (float)(deg > 0 ? deg : 1);
        float acc = (s0 + s1) * inv + bias1[o];
        float xo = xin[(size_t)gn * 16 + o];
#pragma unroll
        for (int i = 0; i < 16; ++i)
            acc += __shfl(xo, i, 16) * root1[i * 16 + o];
        float h = fmaxf(acc, 0.0f);
        sm.xl[node * 16 + o] = h;
        h1g[(size_t)gn * 16 + o] = h;
    }
    int j0 = nb_src[n0];
    int j1 = nb_src[n0 + NPB - 1] + srcdeg[n0 + NPB - 1];
    __syncthreads();

    fused_core(sm, tid, j0, j1, ea, ordsrc, w1, b1, w2, b2, msg2);
}

__global__ __launch_bounds__(256) void node2q_gather(
    const float* __restrict__ h1, const float* __restrict__ msg,
    const int* __restrict__ base_dst, const int* __restrict__ dstdeg,
    const float* __restrict__ root, const float* __restrict__ bias,
    const float* __restrict__ qw, const float* __restrict__ qb,
    float* __restrict__ out)
{
    int t = blockIdx.x * 256 + threadIdx.x;
    int n = t >> 4, o = t & 15;
    if (n >= NN) return;

    int j0 = base_dst[n], deg = dstdeg[n], j1 = j0 + deg;
    float s0 = 0.0f, s1 = 0.0f;
    int j = j0;
    for (; j + 1 < j1; j += 2) {
        s0 += msg[(size_t)j * 16 + o];
        s1 += msg[(size_t)(j + 1) * 16 + o];
    }
    if (j < j1) s0 += msg[(size_t)j * 16 + o];
    float inv = 1.0f / (float)(deg > 0 ? deg : 1);
    float acc = (s0 + s1) * inv + bias[o];

    float xo = h1[(size_t)n * 16 + o];
#pragma unroll
    for (int i = 0; i < 16; ++i)
        acc += __shfl(xo, i, 16) * root[i * 16 + o];

    float q = fmaxf(acc, 0.0f) * qw[o];
#pragma unroll
    for (int d = 8; d >= 1; d >>= 1) q += __shfl_down(q, d, 16);
    if (o == 0) out[n] = q + qb[0];
}

extern "C" void kernel_launch(void* const* d_in, const int* in_sizes, int n_in,
                              void* d_out, int out_size, void* d_ws, size_t ws_size,
                              hipStream_t stream) {
    const float* x     = (const float*)d_in[0];
    const float* ea    = (const float*)d_in[1];
    const float* e1w1  = (const float*)d_in[2];
    const float* e1b1  = (const float*)d_in[3];
    const float* e1w2  = (const float*)d_in[4];
    const float* e1b2  = (const float*)d_in[5];
    const float* root1 = (const float*)d_in[6];
    const float* bias1 = (const float*)d_in[7];
    const float* e2w1  = (const float*)d_in[8];
    const float* e2b1  = (const float*)d_in[9];
    const float* e2w2  = (const float*)d_in[10];
    const float* e2b2  = (const float*)d_in[11];
    const float* root2 = (const float*)d_in[12];
    const float* bias2 = (const float*)d_in[13];
    const float* qw    = (const float*)d_in[14];
    const float* qb    = (const float*)d_in[15];
    const int*   eidx  = (const int*)d_in[16];

    float* msg1     = (float*)d_ws;                  // 16*NE
    float* msg2     = msg1 + (size_t)16 * NE;        // 16*NE
    float* h1       = msg2 + (size_t)16 * NE;        // 16*NN
    int*   dstdeg   = (int*)(h1 + (size_t)16 * NN);  // NN  (memset: dstdeg..gcur)
    int*   srcdeg   = dstdeg + NN;                   // NN
    int*   gcur     = srcdeg + NN;                   // 2
    int*   base_dst = gcur + 2;                      // NN
    int*   cur_dst  = base_dst + NN;                 // NN
    int*   nb_src   = cur_dst + NN;                  // NN
    int*   cur_src  = nb_src + NN;                   // NN
    int2*  ordsrc   = (int2*)(cur_src + NN);         // NE int2

    int eblocks = (NE + 255) / 256;
    int nblocks = (NN * 16 + 255) / 256;

    // --- build (unordered contiguous ranges, per-node counters) ---
    hipMemsetAsync(dstdeg, 0, (size_t)(2 * NN + 2) * sizeof(int), stream);
    hist_kernel<<<eblocks, 256, 0, stream>>>(eidx, dstdeg, srcdeg);
    alloc_kernel<<<2 * ALLOC_BLKS, 256, 0, stream>>>(dstdeg, srcdeg, gcur,
                                                     base_dst, cur_dst,
                                                     nb_src, cur_src);
    fill_kernel<<<eblocks, 256, 0, stream>>>(eidx, cur_dst, cur_src, ordsrc);

    // --- layer 1 edges ---
    edge_fused1<<<NSB, 256, 0, stream>>>(x, ea, ordsrc, nb_src, srcdeg,
                                         e1w1, e1b1, e1w2, e1b2, msg1);
    // --- layer 2 edges (h1 computed in-block) ---
    edge_fused2<<<NSB, 256, 0, stream>>>(x, msg1, base_dst, dstdeg, root1,
                                         bias1, h1, ea, ordsrc, nb_src, srcdeg,
                                         e2w1, e2b1, e2w2, e2b2, msg2);
    // --- final node update + q head ---
    node2q_gather<<<nblocks, 256, 0, stream>>>(h1, msg2, base_dst, dstdeg,
                                               root2, bias2, qw, qb,
                                               (float*)d_out);
}

// Round 9
// 290.982 us; speedup vs baseline: 1.1015x; 1.1015x over previous
//
#include <hip/hip_runtime.h>

#define NN 50000
#define NE 400000
#define NPB 16                         // src nodes per fused block (16 | 256)
#define NSB (NN / NPB)                 // 3125 fused blocks
#define YSTRIDE 276                    // 272 + pad
#define ALLOC_BLKS ((NN + 255) / 256)  // 196 per side

// ws layout (4B units):
//   msg1     float [16*NE]
//   msg2     float [16*NE]
//   h1       float [16*NN]
//   ea_perm  float [8*NE]    edge_attr in src-slot order
//   ord      int   [NE]      pd | (local_node << 19)
//   dstdeg   int   [NN]      (memset zeroes dstdeg, srcdeg, gcur)
//   srcdeg   int   [NN]
//   gcur     int   [2]
//   base_dst int   [NN]
//   cur_dst  int   [NN]
//   nb_src   int   [NN]
//   cur_src  int   [NN]

__global__ __launch_bounds__(256) void hist_kernel(
    const int* __restrict__ eidx, int* __restrict__ dstdeg,
    int* __restrict__ srcdeg)
{
    int e = blockIdx.x * 256 + threadIdx.x;
    if (e < NE) {
        atomicAdd(&srcdeg[eidx[e]], 1);
        atomicAdd(&dstdeg[eidx[NE + e]], 1);
    }
}

__device__ __forceinline__ int block_excl_scan_256(int v, int tid)
{
    __shared__ int wsum[4];
    int lane = tid & 63, w = tid >> 6;
    int incl = v;
#pragma unroll
    for (int d = 1; d < 64; d <<= 1) {
        int t = __shfl_up(incl, d, 64);
        if (lane >= d) incl += t;
    }
    if (lane == 63) wsum[w] = incl;
    __syncthreads();
    if (tid == 0) {
        int s = 0;
#pragma unroll
        for (int k = 0; k < 4; ++k) { int t = wsum[k]; wsum[k] = s; s += t; }
    }
    __syncthreads();
    return incl - v + wsum[w];
}

// Contiguous (globally unordered) range alloc: 256-node chunks, 1 atomic each.
// Within a chunk nodes are ordered; 16 | 256 so each fused block's 16 src
// nodes get one contiguous slot range.
__global__ __launch_bounds__(256) void alloc_kernel(
    const int* __restrict__ dstdeg, const int* __restrict__ srcdeg,
    int* __restrict__ gcur,
    int* __restrict__ base_dst, int* __restrict__ cur_dst,
    int* __restrict__ nb_src, int* __restrict__ cur_src)
{
    __shared__ int base_s;
    int tid = threadIdx.x;
    bool isdst = blockIdx.x < ALLOC_BLKS;
    int i = (isdst ? blockIdx.x : blockIdx.x - ALLOC_BLKS) * 256 + tid;
    int v = (i < NN) ? (isdst ? dstdeg[i] : srcdeg[i]) : 0;
    int excl = block_excl_scan_256(v, tid);
    if (tid == 255) base_s = atomicAdd(isdst ? &gcur[0] : &gcur[1], excl + v);
    __syncthreads();
    int base = base_s + excl;
    if (i < NN) {
        if (isdst) { base_dst[i] = base; cur_dst[i] = base; }
        else       { nb_src[i] = base;  cur_src[i] = base; }
    }
}

// fill + ea permutation: after this, phase 2 of the edge kernels has ZERO
// random reads (ord + ea_perm both stream in src-slot order).
__global__ __launch_bounds__(256) void fill_kernel(
    const int* __restrict__ eidx, const float* __restrict__ ea,
    int* __restrict__ cur_dst, int* __restrict__ cur_src,
    int* __restrict__ ord, float* __restrict__ ea_perm)
{
    int e = blockIdx.x * 256 + threadIdx.x;
    if (e < NE) {
        int s = eidx[e], d = eidx[NE + e];
        int ps = atomicAdd(&cur_src[s], 1);
        int pd = atomicAdd(&cur_dst[d], 1);
        ord[ps] = pd | ((s & 15) << 19);
        const float4* av = (const float4*)(ea + (size_t)e * 8);
        float4 a0 = av[0], a1 = av[1];
        float4* ap = (float4*)(ea_perm + (size_t)ps * 8);
        ap[0] = a0; ap[1] = a1;
    }
}

// ---------------------------------------------------------------------------
// Fused edge kernel. Block = 16 src nodes; LDS 18.7 KB -> 8 blocks/CU.
//   phase 1: Y[node][k][o] = sum_i row[node,i]*w2[k,i,o]  (Y0=b2 at slice 16)
//   phase 2: per src slot j (streaming): hid = relu(ea_perm[j]@w1+b1);
//            msg = Y0 + sum_k hid[k]*Y[k]  -> scattered to dst slot pd.
// ---------------------------------------------------------------------------
struct FusedSmem {
    float xl[NPB * 16];
    float Yl[NPB * YSTRIDE];
};

__device__ __forceinline__ void fused_core(
    FusedSmem& sm, int tid, int j0, int j1,
    const float* __restrict__ ea_perm,
    const int* __restrict__ ord,
    const float* __restrict__ w1, const float* __restrict__ b1,
    const float* __restrict__ w2, const float* __restrict__ b2,
    float* __restrict__ msg_out)
{
    int o = tid & 15;

    // phase 1a: thread (k,o) holds its 16 w2 weights, loops 16 nodes
    {
        int k = tid >> 4;
        float w[16];
#pragma unroll
        for (int i = 0; i < 16; ++i) w[i] = w2[k * 256 + i * 16 + o];
#pragma unroll 4
        for (int node = 0; node < NPB; ++node) {
            const float4* xr = (const float4*)&sm.xl[node * 16];
            float4 x0 = xr[0], x1 = xr[1], x2 = xr[2], x3 = xr[3];
            float acc = x0.x * w[0] + x0.y * w[1] + x0.z * w[2] + x0.w * w[3]
                      + x1.x * w[4] + x1.y * w[5] + x1.z * w[6] + x1.w * w[7]
                      + x2.x * w[8] + x2.y * w[9] + x2.z * w[10] + x2.w * w[11]
                      + x3.x * w[12] + x3.y * w[13] + x3.z * w[14] + x3.w * w[15];
            sm.Yl[node * YSTRIDE + k * 16 + o] = acc;
        }
    }
    // phase 1b: Y0 (=b2) slice; thread (node,o)
    {
        int node = tid >> 4;
        float w[16];
#pragma unroll
        for (int i = 0; i < 16; ++i) w[i] = b2[i * 16 + o];
        const float4* xr = (const float4*)&sm.xl[node * 16];
        float4 x0 = xr[0], x1 = xr[1], x2 = xr[2], x3 = xr[3];
        float acc = x0.x * w[0] + x0.y * w[1] + x0.z * w[2] + x0.w * w[3]
                  + x1.x * w[4] + x1.y * w[5] + x1.z * w[6] + x1.w * w[7]
                  + x2.x * w[8] + x2.y * w[9] + x2.z * w[10] + x2.w * w[11]
                  + x3.x * w[12] + x3.y * w[13] + x3.z * w[14] + x3.w * w[15];
        sm.Yl[node * YSTRIDE + 256 + o] = acc;
    }
    __syncthreads();

    // phase 2: one thread per src slot, all inputs streaming
    for (int j = j0 + tid; j < j1; j += 256) {
        int od = ord[j];
        int pd = od & 0x7FFFF;
        int node = od >> 19;

        const float4* av = (const float4*)(ea_perm + (size_t)j * 8);
        float4 a0 = av[0], a1 = av[1];
        float a[8] = {a0.x, a0.y, a0.z, a0.w, a1.x, a1.y, a1.z, a1.w};

        float hid[16];
#pragma unroll
        for (int jj = 0; jj < 16; ++jj) hid[jj] = b1[jj];
#pragma unroll
        for (int c = 0; c < 8; ++c)
#pragma unroll
            for (int jj = 0; jj < 16; ++jj) hid[jj] += a[c] * w1[c * 16 + jj];
#pragma unroll
        for (int jj = 0; jj < 16; ++jj) hid[jj] = fmaxf(hid[jj], 0.0f);

        const float4* Yr = (const float4*)&sm.Yl[node * YSTRIDE];
        float4 m0 = Yr[64], m1 = Yr[65], m2 = Yr[66], m3 = Yr[67];
#pragma unroll
        for (int k = 0; k < 16; ++k) {
            float hk = hid[k];
            float4 y0 = Yr[k * 4 + 0], y1 = Yr[k * 4 + 1];
            float4 y2 = Yr[k * 4 + 2], y3 = Yr[k * 4 + 3];
            m0.x = fmaf(hk, y0.x, m0.x); m0.y = fmaf(hk, y0.y, m0.y);
            m0.z = fmaf(hk, y0.z, m0.z); m0.w = fmaf(hk, y0.w, m0.w);
            m1.x = fmaf(hk, y1.x, m1.x); m1.y = fmaf(hk, y1.y, m1.y);
            m1.z = fmaf(hk, y1.z, m1.z); m1.w = fmaf(hk, y1.w, m1.w);
            m2.x = fmaf(hk, y2.x, m2.x); m2.y = fmaf(hk, y2.y, m2.y);
            m2.z = fmaf(hk, y2.z, m2.z); m2.w = fmaf(hk, y2.w, m2.w);
            m3.x = fmaf(hk, y3.x, m3.x); m3.y = fmaf(hk, y3.y, m3.y);
            m3.z = fmaf(hk, y3.z, m3.z); m3.w = fmaf(hk, y3.w, m3.w);
        }
        float4* mp = (float4*)(msg_out + (size_t)pd * 16);
        mp[0] = m0; mp[1] = m1; mp[2] = m2; mp[3] = m3;
    }
}

__global__ __launch_bounds__(256, 4) void edge_fused(
    const float* __restrict__ xin, const float* __restrict__ ea_perm,
    const int* __restrict__ ord,
    const int* __restrict__ nb_src, const int* __restrict__ srcdeg,
    const float* __restrict__ w1, const float* __restrict__ b1,
    const float* __restrict__ w2, const float* __restrict__ b2,
    float* __restrict__ msg)
{
    __shared__ FusedSmem sm;
    int tid = threadIdx.x;
    int n0 = blockIdx.x * NPB;

    sm.xl[tid] = xin[(size_t)n0 * 16 + tid];  // 16 nodes x 16 ch, coalesced
    int j0 = nb_src[n0];
    int j1 = nb_src[n0 + NPB - 1] + srcdeg[n0 + NPB - 1];
    __syncthreads();

    fused_core(sm, tid, j0, j1, ea_perm, ord, w1, b1, w2, b2, msg);
}

// ---------------------------------------------------------------------------
// Node kernels: 16 lanes/node, lane o = channel o; per-node msg ranges are
// contiguous (globally unordered) -> streaming reads.
// ---------------------------------------------------------------------------
__global__ __launch_bounds__(256) void node1_gather(
    const float* __restrict__ x, const float* __restrict__ msg,
    const int* __restrict__ base_dst, const int* __restrict__ dstdeg,
    const float* __restrict__ root, const float* __restrict__ bias,
    float* __restrict__ out)
{
    int t = blockIdx.x * 256 + threadIdx.x;
    int n = t >> 4, o = t & 15;
    if (n >= NN) return;

    int j0 = base_dst[n], deg = dstdeg[n], j1 = j0 + deg;
    float s0 = 0.0f, s1 = 0.0f;
    int j = j0;
    for (; j + 1 < j1; j += 2) {
        s0 += msg[(size_t)j * 16 + o];
        s1 += msg[(size_t)(j + 1) * 16 + o];
    }
    if (j < j1) s0 += msg[(size_t)j * 16 + o];
    float inv = 1.0f / (float)(deg > 0 ? deg : 1);
    float acc = (s0 + s1) * inv + bias[o];

    float xo = x[(size_t)n * 16 + o];
#pragma unroll
    for (int i = 0; i < 16; ++i)
        acc += __shfl(xo, i, 16) * root[i * 16 + o];

    out[(size_t)n * 16 + o] = fmaxf(acc, 0.0f);
}

__global__ __launch_bounds__(256) void node2q_gather(
    const float* __restrict__ h1, const float* __restrict__ msg,
    const int* __restrict__ base_dst, const int* __restrict__ dstdeg,
    const float* __restrict__ root, const float* __restrict__ bias,
    const float* __restrict__ qw, const float* __restrict__ qb,
    float* __restrict__ out)
{
    int t = blockIdx.x * 256 + threadIdx.x;
    int n = t >> 4, o = t & 15;
    if (n >= NN) return;

    int j0 = base_dst[n], deg = dstdeg[n], j1 = j0 + deg;
    float s0 = 0.0f, s1 = 0.0f;
    int j = j0;
    for (; j + 1 < j1; j += 2) {
        s0 += msg[(size_t)j * 16 + o];
        s1 += msg[(size_t)(j + 1) * 16 + o];
    }
    if (j < j1) s0 += msg[(size_t)j * 16 + o];
    float inv = 1.0f / (float)(deg > 0 ? deg : 1);
    float acc = (s0 + s1) * inv + bias[o];

    float xo = h1[(size_t)n * 16 + o];
#pragma unroll
    for (int i = 0; i < 16; ++i)
        acc += __shfl(xo, i, 16) * root[i * 16 + o];

    float q = fmaxf(acc, 0.0f) * qw[o];
#pragma unroll
    for (int d = 8; d >= 1; d >>= 1) q += __shfl_down(q, d, 16);
    if (o == 0) out[n] = q + qb[0];
}

extern "C" void kernel_launch(void* const* d_in, const int* in_sizes, int n_in,
                              void* d_out, int out_size, void* d_ws, size_t ws_size,
                              hipStream_t stream) {
    const float* x     = (const float*)d_in[0];
    const float* ea    = (const float*)d_in[1];
    const float* e1w1  = (const float*)d_in[2];
    const float* e1b1  = (const float*)d_in[3];
    const float* e1w2  = (const float*)d_in[4];
    const float* e1b2  = (const float*)d_in[5];
    const float* root1 = (const float*)d_in[6];
    const float* bias1 = (const float*)d_in[7];
    const float* e2w1  = (const float*)d_in[8];
    const float* e2b1  = (const float*)d_in[9];
    const float* e2w2  = (const float*)d_in[10];
    const float* e2b2  = (const float*)d_in[11];
    const float* root2 = (const float*)d_in[12];
    const float* bias2 = (const float*)d_in[13];
    const float* qw    = (const float*)d_in[14];
    const float* qb    = (const float*)d_in[15];
    const int*   eidx  = (const int*)d_in[16];

    float* msg1     = (float*)d_ws;                  // 16*NE
    float* msg2     = msg1 + (size_t)16 * NE;        // 16*NE
    float* h1       = msg2 + (size_t)16 * NE;        // 16*NN
    float* ea_perm  = h1 + (size_t)16 * NN;          // 8*NE
    int*   ord      = (int*)(ea_perm + (size_t)8 * NE);  // NE
    int*   dstdeg   = ord + NE;                      // NN  (memset: dstdeg..gcur)
    int*   srcdeg   = dstdeg + NN;                   // NN
    int*   gcur     = srcdeg + NN;                   // 2
    int*   base_dst = gcur + 2;                      // NN
    int*   cur_dst  = base_dst + NN;                 // NN
    int*   nb_src   = cur_dst + NN;                  // NN
    int*   cur_src  = nb_src + NN;                   // NN

    int eblocks = (NE + 255) / 256;
    int nblocks = (NN * 16 + 255) / 256;

    // --- build ---
    hipMemsetAsync(dstdeg, 0, (size_t)(2 * NN + 2) * sizeof(int), stream);
    hist_kernel<<<eblocks, 256, 0, stream>>>(eidx, dstdeg, srcdeg);
    alloc_kernel<<<2 * ALLOC_BLKS, 256, 0, stream>>>(dstdeg, srcdeg, gcur,
                                                     base_dst, cur_dst,
                                                     nb_src, cur_src);
    fill_kernel<<<eblocks, 256, 0, stream>>>(eidx, ea, cur_dst, cur_src,
                                             ord, ea_perm);

    // --- layer 1 ---
    edge_fused<<<NSB, 256, 0, stream>>>(x, ea_perm, ord, nb_src, srcdeg,
                                        e1w1, e1b1, e1w2, e1b2, msg1);
    node1_gather<<<nblocks, 256, 0, stream>>>(x, msg1, base_dst, dstdeg, root1,
                                              bias1, h1);

    // --- layer 2 + q head ---
    edge_fused<<<NSB, 256, 0, stream>>>(h1, ea_perm, ord, nb_src, srcdeg,
                                        e2w1, e2b1, e2w2, e2b2, msg2);
    node2q_gather<<<nblocks, 256, 0, stream>>>(h1, msg2, base_dst, dstdeg,
                                               root2, bias2, qw, qb,
                                               (float*)d_out);
}